// Round 1
// baseline (473.355 us; speedup 1.0000x reference)
//
#include <hip/hip_runtime.h>
#include <hip/hip_bf16.h>

#define NQ 65536
#define DIM 512
#define HID 256
#define NWAY 5
#define NKPTS 17
#define NS 25

typedef short bf16x8 __attribute__((ext_vector_type(8)));
typedef float f32x4 __attribute__((ext_vector_type(4)));
typedef _Float16 half8 __attribute__((ext_vector_type(8)));

static __device__ __forceinline__ unsigned short f2bf(float f) {
    unsigned int x = __float_as_uint(f);
    unsigned int r = (x + 0x7fffu + ((x >> 16) & 1u)) >> 16;
    return (unsigned short)r;
}

// ---------------- support MLP: h = relu(sf@W1+b1)@W2+b2  (25 x 512) ----------------
__global__ __launch_bounds__(256) void k_support(const float* __restrict__ sf,
                                                 const float* __restrict__ W1, const float* __restrict__ b1,
                                                 const float* __restrict__ W2, const float* __restrict__ b2,
                                                 float* __restrict__ ws_h) {
    __shared__ float s_in[DIM];
    __shared__ float s_h1[DIM];
    int s = blockIdx.x;
    int t = threadIdx.x;
    for (int i = t; i < DIM; i += 256) s_in[i] = sf[s * DIM + i];
    __syncthreads();
    for (int cc = 0; cc < 2; cc++) {
        int c = t + cc * 256;
        float acc = b1[c];
        #pragma unroll 8
        for (int k = 0; k < DIM; k++) acc += s_in[k] * W1[k * DIM + c];
        s_h1[c] = fmaxf(acc, 0.0f);
    }
    __syncthreads();
    for (int cc = 0; cc < 2; cc++) {
        int c = t + cc * 256;
        float acc = b2[c];
        #pragma unroll 8
        for (int k = 0; k < DIM; k++) acc += s_h1[k] * W2[k * DIM + c];
        ws_h[s * DIM + c] = acc;
    }
}

// ---------------- prototypes: mean over shots, norm, broadcast out ----------------
__global__ __launch_bounds__(256) void k_proto(const float* __restrict__ ws_h,
                                               float* __restrict__ ws_proto, float* __restrict__ ws_pn,
                                               float* __restrict__ out_proto) {
    int w = blockIdx.x, t = threadIdx.x;
    __shared__ float s_p[DIM];
    __shared__ float red[256];
    for (int i = t; i < DIM; i += 256) {
        float a = 0.0f;
        for (int s = 0; s < 5; s++) a += ws_h[(w * 5 + s) * DIM + i];
        a *= 0.2f;
        s_p[i] = a;
        ws_proto[w * DIM + i] = a;
    }
    __syncthreads();
    float qq = 0.0f;
    for (int i = t; i < DIM; i += 256) qq += s_p[i] * s_p[i];
    red[t] = qq;
    __syncthreads();
    for (int s2 = 128; s2 > 0; s2 >>= 1) {
        if (t < s2) red[t] += red[t + s2];
        __syncthreads();
    }
    if (t == 0) ws_pn[w] = sqrtf(red[0]);
    for (int i = t; i < NKPTS * DIM; i += 256)
        out_proto[(size_t)w * NKPTS * DIM + i] = s_p[i & (DIM - 1)];
}

// ---------------- convert [Wo1|Wc1] -> bf16, transposed: wb[c*512+k] = W[k][c] ----------------
__global__ __launch_bounds__(256) void k_convw(const float* __restrict__ Wo1, const float* __restrict__ Wc1,
                                               unsigned short* __restrict__ wb) {
    int c = blockIdx.x;
    const float* src = (c < 256) ? Wo1 : Wc1;
    int cc = (c < 256) ? c : (c - 256);
    for (int k = threadIdx.x; k < DIM; k += 256)
        wb[c * DIM + k] = f2bf(src[k * HID + cc]);
}

// ---------------- distances (pure f32) + argmin ----------------
__global__ __launch_bounds__(256) void k_dist(const float* __restrict__ qf,
                                              const float* __restrict__ ws_proto, const float* __restrict__ ws_pn,
                                              const float* __restrict__ temp_p,
                                              float* __restrict__ out_dist, float* __restrict__ out_class) {
    int gwave = (int)((blockIdx.x * 256 + threadIdx.x) >> 6);  // 0..4095
    int lane = threadIdx.x & 63;
    float p[NWAY][8];
    #pragma unroll
    for (int w = 0; w < NWAY; w++)
        #pragma unroll
        for (int j = 0; j < 8; j++) p[w][j] = ws_proto[w * DIM + lane * 8 + j];
    float pn[NWAY];
    #pragma unroll
    for (int w = 0; w < NWAY; w++) pn[w] = ws_pn[w];
    float invt = 1.0f / temp_p[0];

    for (int qi = 0; qi < 16; qi++) {
        int q = gwave * 16 + qi;
        const float4* qp = (const float4*)(qf + (size_t)q * DIM + lane * 8);
        float4 a = qp[0], b = qp[1];
        float qv[8] = {a.x, a.y, a.z, a.w, b.x, b.y, b.z, b.w};
        float s[6] = {0, 0, 0, 0, 0, 0};
        #pragma unroll
        for (int j = 0; j < 8; j++) {
            float v = qv[j];
            s[5] += v * v;
            #pragma unroll
            for (int w = 0; w < NWAY; w++) s[w] += v * p[w][j];
        }
        #pragma unroll
        for (int off = 32; off > 0; off >>= 1)
            #pragma unroll
            for (int k = 0; k < 6; k++) s[k] += __shfl_xor(s[k], off, 64);
        float qn = sqrtf(s[5]);
        float d[NWAY];
        #pragma unroll
        for (int w = 0; w < NWAY; w++) {
            float den = fmaxf(qn * pn[w], 1e-8f);
            d[w] = (1.0f - s[w] / den) * invt;
        }
        int am = 0;
        float mv = d[0];
        #pragma unroll
        for (int w = 1; w < NWAY; w++)
            if (d[w] < mv) { mv = d[w]; am = w; }
        float* od = out_dist + (size_t)q * (NWAY * NKPTS);
        od[lane] = d[lane / 17];
        if (lane < 21) od[64 + lane] = d[(64 + lane) / 17];
        if (lane == 0) out_class[q] = (float)am;
    }
}

// ---------------- fused MFMA GEMM + head epilogue ----------------
// grid: (NQ/64) * 2 blocks; nb=0 -> offset head (Wo1 half), nb=1 -> confidence head (Wc1 half)
__global__ __launch_bounds__(256) void k_gemm(const float* __restrict__ qf, const unsigned short* __restrict__ wb,
                                              const float* __restrict__ bo1, const float* __restrict__ Wo2,
                                              const float* __restrict__ bo2,
                                              const float* __restrict__ bc1, const float* __restrict__ Wc2,
                                              const float* __restrict__ bc2,
                                              const float* __restrict__ ic,
                                              float* __restrict__ out_kp, float* __restrict__ out_conf) {
    __shared__ __align__(16) char smem[34560];
    unsigned short* Alds = (unsigned short*)smem;            // 64 rows x stride 40 bf16
    unsigned short* Blds = (unsigned short*)(smem + 5120);   // 256 rows x stride 40 bf16
    _Float16* hlds = (_Float16*)smem;                        // epilogue: 64 x stride 264 f16
    float* offlds = (float*)(smem + 33792);                  // 128 f32

    int bx = blockIdx.x;
    int mb = bx >> 1;
    int nb = bx & 1;
    int t = threadIdx.x;
    int wv = t >> 6;
    int lane = t & 63;
    int r = lane & 15;
    int q8 = (lane >> 4) * 8;

    f32x4 acc[4][4];
    #pragma unroll
    for (int i = 0; i < 4; i++)
        #pragma unroll
        for (int j = 0; j < 4; j++) {
            f32x4 z = {0.0f, 0.0f, 0.0f, 0.0f};
            acc[i][j] = z;
        }

    int am = t >> 2;
    int akc = t & 3;
    const float* aptr = qf + ((size_t)(mb * 64 + am)) * DIM + akc * 8;
    const unsigned short* bptr = wb + ((size_t)(nb * 256 + t)) * DIM;

    for (int it = 0; it < 16; it++) {
        int k0 = it * 32;
        float4 a0 = *(const float4*)(aptr + k0);
        float4 a1 = *(const float4*)(aptr + k0 + 4);
        unsigned int p0 = f2bf(a0.x) | ((unsigned int)f2bf(a0.y) << 16);
        unsigned int p1 = f2bf(a0.z) | ((unsigned int)f2bf(a0.w) << 16);
        unsigned int p2 = f2bf(a1.x) | ((unsigned int)f2bf(a1.y) << 16);
        unsigned int p3 = f2bf(a1.z) | ((unsigned int)f2bf(a1.w) << 16);
        uint4 b0 = *(const uint4*)(bptr + k0);
        uint4 b1 = *(const uint4*)(bptr + k0 + 8);
        uint4 b2 = *(const uint4*)(bptr + k0 + 16);
        uint4 b3 = *(const uint4*)(bptr + k0 + 24);
        __syncthreads();  // previous iter's frag reads complete
        *(uint4*)(Alds + am * 40 + akc * 8) = make_uint4(p0, p1, p2, p3);
        *(uint4*)(Blds + t * 40) = b0;
        *(uint4*)(Blds + t * 40 + 8) = b1;
        *(uint4*)(Blds + t * 40 + 16) = b2;
        *(uint4*)(Blds + t * 40 + 24) = b3;
        __syncthreads();
        bf16x8 af[4], bf[4];
        #pragma unroll
        for (int mt = 0; mt < 4; mt++)
            af[mt] = *(const bf16x8*)(Alds + (mt * 16 + r) * 40 + q8);
        #pragma unroll
        for (int nt = 0; nt < 4; nt++)
            bf[nt] = *(const bf16x8*)(Blds + (wv * 64 + nt * 16 + r) * 40 + q8);
        #pragma unroll
        for (int mt = 0; mt < 4; mt++)
            #pragma unroll
            for (int nt = 0; nt < 4; nt++)
                acc[mt][nt] = __builtin_amdgcn_mfma_f32_16x16x32_bf16(af[mt], bf[nt], acc[mt][nt], 0, 0, 0);
    }
    __syncthreads();
    // bias + relu + store h tile to LDS as f16 (C layout: row=(lane>>4)*4+rg (M), col=lane&15 (N))
    const float* bias = nb ? bc1 : bo1;
    #pragma unroll
    for (int nt = 0; nt < 4; nt++) {
        int cl = wv * 64 + nt * 16 + r;  // 0..255
        float bv = bias[cl];
        #pragma unroll
        for (int mt = 0; mt < 4; mt++)
            #pragma unroll
            for (int rg = 0; rg < 4; rg++) {
                int ml = mt * 16 + (lane >> 4) * 4 + rg;
                float v = acc[mt][nt][rg] + bv;
                hlds[ml * 264 + cl] = (_Float16)fmaxf(v, 0.0f);
            }
    }
    __syncthreads();

    if (nb == 0) {
        if (t < 64) {
            float ox = bo2[0], oy = bo2[1];
            for (int c0 = 0; c0 < 256; c0 += 8) {
                half8 hv = *(const half8*)(hlds + t * 264 + c0);
                #pragma unroll
                for (int j = 0; j < 8; j++) {
                    float hf = (float)hv[j];
                    ox += hf * Wo2[(c0 + j) * 2];
                    oy += hf * Wo2[(c0 + j) * 2 + 1];
                }
            }
            offlds[t * 2] = ox;
            offlds[t * 2 + 1] = oy;
        }
        __syncthreads();
        for (int i = t; i < 64 * 34; i += 256) {
            int q = i / 34;
            int rem = i - q * 34;
            int j = rem & 1;
            size_t Q = (size_t)mb * 64 + q;
            float o = offlds[q * 2 + j];
            float sg = 1.0f / (1.0f + __expf(-o));
            out_kp[Q * 34 + rem] = sg * ic[Q * 2 + j];
        }
    } else {
        if (t < 64) {
            float cl2 = bc2[0];
            for (int c0 = 0; c0 < 256; c0 += 8) {
                half8 hv = *(const half8*)(hlds + t * 264 + c0);
                #pragma unroll
                for (int j = 0; j < 8; j++) cl2 += (float)hv[j] * Wc2[c0 + j];
            }
            offlds[t] = 1.0f / (1.0f + __expf(-cl2));
        }
        __syncthreads();
        for (int i = t; i < 64 * 17; i += 256) {
            int q = i / 17;
            out_conf[(size_t)mb * 64 * 17 + i] = offlds[q];
        }
    }
}

extern "C" void kernel_launch(void* const* d_in, const int* in_sizes, int n_in,
                              void* d_out, int out_size, void* d_ws, size_t ws_size,
                              hipStream_t stream) {
    const float* sf = (const float*)d_in[0];
    const float* qf = (const float*)d_in[2];
    const float* ic = (const float*)d_in[3];
    const float* W1 = (const float*)d_in[4];
    const float* b1 = (const float*)d_in[5];
    const float* W2 = (const float*)d_in[6];
    const float* b2 = (const float*)d_in[7];
    const float* Wo1 = (const float*)d_in[8];
    const float* bo1 = (const float*)d_in[9];
    const float* Wo2 = (const float*)d_in[10];
    const float* bo2 = (const float*)d_in[11];
    const float* Wc1 = (const float*)d_in[12];
    const float* bc1 = (const float*)d_in[13];
    const float* Wc2 = (const float*)d_in[14];
    const float* bc2 = (const float*)d_in[15];
    const float* temp = (const float*)d_in[16];

    float* out = (float*)d_out;
    float* out_kp = out;                   // 65536*17*2
    float* out_conf = out + 2228224;       // 65536*17
    float* out_dist = out + 3342336;       // 65536*5*17
    float* out_class = out + 8912896;      // 65536
    float* out_proto = out + 8978432;      // 5*17*512

    char* ws = (char*)d_ws;
    float* ws_h = (float*)ws;                              // 25*512 f32
    float* ws_proto = (float*)(ws + 51200);                // 5*512 f32
    float* ws_pn = (float*)(ws + 61440);                   // 5 f32
    unsigned short* ws_wb = (unsigned short*)(ws + 65536); // 512*512 bf16 (transposed [Wo1|Wc1])

    hipLaunchKernelGGL(k_support, dim3(25), dim3(256), 0, stream, sf, W1, b1, W2, b2, ws_h);
    hipLaunchKernelGGL(k_proto, dim3(5), dim3(256), 0, stream, ws_h, ws_proto, ws_pn, out_proto);
    hipLaunchKernelGGL(k_convw, dim3(512), dim3(256), 0, stream, Wo1, Wc1, ws_wb);
    hipLaunchKernelGGL(k_dist, dim3(1024), dim3(256), 0, stream, qf, ws_proto, ws_pn, temp, out_dist, out_class);
    hipLaunchKernelGGL(k_gemm, dim3(2048), dim3(256), 0, stream, qf, ws_wb, bo1, Wo2, bo2, bc1, Wc2, bc2, ic, out_kp, out_conf);
}

// Round 2
// 398.464 us; speedup vs baseline: 1.1879x; 1.1879x over previous
//
#include <hip/hip_runtime.h>
#include <hip/hip_bf16.h>

#define NQ 65536
#define DIM 512
#define HID 256
#define NWAY 5
#define NKPTS 17
#define NS 25

typedef short bf16x8 __attribute__((ext_vector_type(8)));
typedef float f32x4 __attribute__((ext_vector_type(4)));
typedef _Float16 half8 __attribute__((ext_vector_type(8)));

static __device__ __forceinline__ unsigned short f2bf(float f) {
    unsigned int x = __float_as_uint(f);
    unsigned int r = (x + 0x7fffu + ((x >> 16) & 1u)) >> 16;
    return (unsigned short)r;
}

// ---------------- support MLP layer: out[s][c] = (relu?) (in[s]·W[:,c] + b[c]) ----------------
// wave-per-output: 25*512 = 12800 waves = 3200 blocks x 4 waves. Latency hidden by occupancy
// (vs R0's 25-block version: 131 us at 1.1% occupancy).
__global__ __launch_bounds__(256) void k_sup(const float* __restrict__ in,
                                             const float* __restrict__ W, const float* __restrict__ b,
                                             float* __restrict__ out, int relu) {
    int w = blockIdx.x * 4 + (threadIdx.x >> 6);   // 0..12799
    int lane = threadIdx.x & 63;
    int s = w >> 9;          // 0..24
    int c = w & 511;         // 0..511
    const float* ip = in + s * DIM + lane * 8;
    float4 a0 = *(const float4*)ip;
    float4 a1 = *(const float4*)(ip + 4);
    float av[8] = {a0.x, a0.y, a0.z, a0.w, a1.x, a1.y, a1.z, a1.w};
    float acc = 0.0f;
    #pragma unroll
    for (int j = 0; j < 8; j++)
        acc += av[j] * W[(lane * 8 + j) * DIM + c];
    #pragma unroll
    for (int off = 32; off > 0; off >>= 1)
        acc += __shfl_xor(acc, off, 64);
    if (lane == 0) {
        float v = acc + b[c];
        out[s * DIM + c] = relu ? fmaxf(v, 0.0f) : v;
    }
}

// ---------------- prototypes: mean over shots, norm, broadcast out ----------------
__global__ __launch_bounds__(256) void k_proto(const float* __restrict__ ws_h,
                                               float* __restrict__ ws_proto, float* __restrict__ ws_pn,
                                               float* __restrict__ out_proto) {
    int w = blockIdx.x, t = threadIdx.x;
    __shared__ float s_p[DIM];
    __shared__ float red[256];
    for (int i = t; i < DIM; i += 256) {
        float a = 0.0f;
        for (int s = 0; s < 5; s++) a += ws_h[(w * 5 + s) * DIM + i];
        a *= 0.2f;
        s_p[i] = a;
        ws_proto[w * DIM + i] = a;
    }
    __syncthreads();
    float qq = 0.0f;
    for (int i = t; i < DIM; i += 256) qq += s_p[i] * s_p[i];
    red[t] = qq;
    __syncthreads();
    for (int s2 = 128; s2 > 0; s2 >>= 1) {
        if (t < s2) red[t] += red[t + s2];
        __syncthreads();
    }
    if (t == 0) ws_pn[w] = sqrtf(red[0]);
    for (int i = t; i < NKPTS * DIM; i += 256)
        out_proto[(size_t)w * NKPTS * DIM + i] = s_p[i & (DIM - 1)];
}

// ---------------- convert [Wo1|Wc1] -> bf16, transposed: wb[c*512+k] = W[k][c] ----------------
__global__ __launch_bounds__(256) void k_convw(const float* __restrict__ Wo1, const float* __restrict__ Wc1,
                                               unsigned short* __restrict__ wb) {
    int c = blockIdx.x;
    const float* src = (c < 256) ? Wo1 : Wc1;
    int cc = (c < 256) ? c : (c - 256);
    for (int k = threadIdx.x; k < DIM; k += 256)
        wb[c * DIM + k] = f2bf(src[k * HID + cc]);
}

// ---------------- distances (pure f32) + argmin ----------------
__global__ __launch_bounds__(256) void k_dist(const float* __restrict__ qf,
                                              const float* __restrict__ ws_proto, const float* __restrict__ ws_pn,
                                              const float* __restrict__ temp_p,
                                              float* __restrict__ out_dist, float* __restrict__ out_class) {
    int gwave = (int)((blockIdx.x * 256 + threadIdx.x) >> 6);  // 0..4095
    int lane = threadIdx.x & 63;
    float p[NWAY][8];
    #pragma unroll
    for (int w = 0; w < NWAY; w++)
        #pragma unroll
        for (int j = 0; j < 8; j++) p[w][j] = ws_proto[w * DIM + lane * 8 + j];
    float pn[NWAY];
    #pragma unroll
    for (int w = 0; w < NWAY; w++) pn[w] = ws_pn[w];
    float invt = 1.0f / temp_p[0];

    for (int qi = 0; qi < 16; qi++) {
        int q = gwave * 16 + qi;
        const float4* qp = (const float4*)(qf + (size_t)q * DIM + lane * 8);
        float4 a = qp[0], b = qp[1];
        float qv[8] = {a.x, a.y, a.z, a.w, b.x, b.y, b.z, b.w};
        float s[6] = {0, 0, 0, 0, 0, 0};
        #pragma unroll
        for (int j = 0; j < 8; j++) {
            float v = qv[j];
            s[5] += v * v;
            #pragma unroll
            for (int w = 0; w < NWAY; w++) s[w] += v * p[w][j];
        }
        #pragma unroll
        for (int off = 32; off > 0; off >>= 1)
            #pragma unroll
            for (int k = 0; k < 6; k++) s[k] += __shfl_xor(s[k], off, 64);
        float qn = sqrtf(s[5]);
        float d[NWAY];
        #pragma unroll
        for (int w = 0; w < NWAY; w++) {
            float den = fmaxf(qn * pn[w], 1e-8f);
            d[w] = (1.0f - s[w] / den) * invt;
        }
        int am = 0;
        float mv = d[0];
        #pragma unroll
        for (int w = 1; w < NWAY; w++)
            if (d[w] < mv) { mv = d[w]; am = w; }
        float* od = out_dist + (size_t)q * (NWAY * NKPTS);
        od[lane] = d[lane / 17];
        if (lane < 21) od[64 + lane] = d[(64 + lane) / 17];
        if (lane == 0) out_class[q] = (float)am;
    }
}

// ---------------- fused MFMA GEMM + head epilogue ----------------
// grid: (NQ/64) * 2 blocks; nb=0 -> offset head (Wo1 half), nb=1 -> confidence head (Wc1 half)
__global__ __launch_bounds__(256) void k_gemm(const float* __restrict__ qf, const unsigned short* __restrict__ wb,
                                              const float* __restrict__ bo1, const float* __restrict__ Wo2,
                                              const float* __restrict__ bo2,
                                              const float* __restrict__ bc1, const float* __restrict__ Wc2,
                                              const float* __restrict__ bc2,
                                              const float* __restrict__ ic,
                                              float* __restrict__ out_kp, float* __restrict__ out_conf) {
    __shared__ __align__(16) char smem[34560];
    unsigned short* Alds = (unsigned short*)smem;            // 64 rows x stride 40 bf16
    unsigned short* Blds = (unsigned short*)(smem + 5120);   // 256 rows x stride 40 bf16
    _Float16* hlds = (_Float16*)smem;                        // epilogue: 64 x stride 264 f16
    float* offlds = (float*)(smem + 33792);                  // 128 f32

    int bx = blockIdx.x;
    int mb = bx >> 1;
    int nb = bx & 1;
    int t = threadIdx.x;
    int wv = t >> 6;
    int lane = t & 63;
    int r = lane & 15;
    int q8 = (lane >> 4) * 8;

    f32x4 acc[4][4];
    #pragma unroll
    for (int i = 0; i < 4; i++)
        #pragma unroll
        for (int j = 0; j < 4; j++) {
            f32x4 z = {0.0f, 0.0f, 0.0f, 0.0f};
            acc[i][j] = z;
        }

    int am = t >> 2;
    int akc = t & 3;
    const float* aptr = qf + ((size_t)(mb * 64 + am)) * DIM + akc * 8;
    const unsigned short* bptr = wb + ((size_t)(nb * 256 + t)) * DIM;

    for (int it = 0; it < 16; it++) {
        int k0 = it * 32;
        float4 a0 = *(const float4*)(aptr + k0);
        float4 a1 = *(const float4*)(aptr + k0 + 4);
        unsigned int p0 = f2bf(a0.x) | ((unsigned int)f2bf(a0.y) << 16);
        unsigned int p1 = f2bf(a0.z) | ((unsigned int)f2bf(a0.w) << 16);
        unsigned int p2 = f2bf(a1.x) | ((unsigned int)f2bf(a1.y) << 16);
        unsigned int p3 = f2bf(a1.z) | ((unsigned int)f2bf(a1.w) << 16);
        uint4 b0 = *(const uint4*)(bptr + k0);
        uint4 b1 = *(const uint4*)(bptr + k0 + 8);
        uint4 b2 = *(const uint4*)(bptr + k0 + 16);
        uint4 b3 = *(const uint4*)(bptr + k0 + 24);
        __syncthreads();  // previous iter's frag reads complete
        *(uint4*)(Alds + am * 40 + akc * 8) = make_uint4(p0, p1, p2, p3);
        *(uint4*)(Blds + t * 40) = b0;
        *(uint4*)(Blds + t * 40 + 8) = b1;
        *(uint4*)(Blds + t * 40 + 16) = b2;
        *(uint4*)(Blds + t * 40 + 24) = b3;
        __syncthreads();
        bf16x8 af[4], bf[4];
        #pragma unroll
        for (int mt = 0; mt < 4; mt++)
            af[mt] = *(const bf16x8*)(Alds + (mt * 16 + r) * 40 + q8);
        #pragma unroll
        for (int nt = 0; nt < 4; nt++)
            bf[nt] = *(const bf16x8*)(Blds + (wv * 64 + nt * 16 + r) * 40 + q8);
        #pragma unroll
        for (int mt = 0; mt < 4; mt++)
            #pragma unroll
            for (int nt = 0; nt < 4; nt++)
                acc[mt][nt] = __builtin_amdgcn_mfma_f32_16x16x32_bf16(af[mt], bf[nt], acc[mt][nt], 0, 0, 0);
    }
    __syncthreads();
    // bias + relu + store h tile to LDS as f16 (C layout: row=(lane>>4)*4+rg (M), col=lane&15 (N))
    const float* bias = nb ? bc1 : bo1;
    #pragma unroll
    for (int nt = 0; nt < 4; nt++) {
        int cl = wv * 64 + nt * 16 + r;  // 0..255
        float bv = bias[cl];
        #pragma unroll
        for (int mt = 0; mt < 4; mt++)
            #pragma unroll
            for (int rg = 0; rg < 4; rg++) {
                int ml = mt * 16 + (lane >> 4) * 4 + rg;
                float v = acc[mt][nt][rg] + bv;
                hlds[ml * 264 + cl] = (_Float16)fmaxf(v, 0.0f);
            }
    }
    __syncthreads();

    if (nb == 0) {
        if (t < 64) {
            float ox = bo2[0], oy = bo2[1];
            for (int c0 = 0; c0 < 256; c0 += 8) {
                half8 hv = *(const half8*)(hlds + t * 264 + c0);
                #pragma unroll
                for (int j = 0; j < 8; j++) {
                    float hf = (float)hv[j];
                    ox += hf * Wo2[(c0 + j) * 2];
                    oy += hf * Wo2[(c0 + j) * 2 + 1];
                }
            }
            offlds[t * 2] = ox;
            offlds[t * 2 + 1] = oy;
        }
        __syncthreads();
        for (int i = t; i < 64 * 34; i += 256) {
            int q = i / 34;
            int rem = i - q * 34;
            int j = rem & 1;
            size_t Q = (size_t)mb * 64 + q;
            float o = offlds[q * 2 + j];
            float sg = 1.0f / (1.0f + __expf(-o));
            out_kp[Q * 34 + rem] = sg * ic[Q * 2 + j];
        }
    } else {
        if (t < 64) {
            float cl2 = bc2[0];
            for (int c0 = 0; c0 < 256; c0 += 8) {
                half8 hv = *(const half8*)(hlds + t * 264 + c0);
                #pragma unroll
                for (int j = 0; j < 8; j++) cl2 += (float)hv[j] * Wc2[c0 + j];
            }
            offlds[t] = 1.0f / (1.0f + __expf(-cl2));
        }
        __syncthreads();
        for (int i = t; i < 64 * 17; i += 256) {
            int q = i / 17;
            out_conf[(size_t)mb * 64 * 17 + i] = offlds[q];
        }
    }
}

extern "C" void kernel_launch(void* const* d_in, const int* in_sizes, int n_in,
                              void* d_out, int out_size, void* d_ws, size_t ws_size,
                              hipStream_t stream) {
    const float* sf = (const float*)d_in[0];
    const float* qf = (const float*)d_in[2];
    const float* ic = (const float*)d_in[3];
    const float* W1 = (const float*)d_in[4];
    const float* b1 = (const float*)d_in[5];
    const float* W2 = (const float*)d_in[6];
    const float* b2 = (const float*)d_in[7];
    const float* Wo1 = (const float*)d_in[8];
    const float* bo1 = (const float*)d_in[9];
    const float* Wo2 = (const float*)d_in[10];
    const float* bo2 = (const float*)d_in[11];
    const float* Wc1 = (const float*)d_in[12];
    const float* bc1 = (const float*)d_in[13];
    const float* Wc2 = (const float*)d_in[14];
    const float* bc2 = (const float*)d_in[15];
    const float* temp = (const float*)d_in[16];

    float* out = (float*)d_out;
    float* out_kp = out;                   // 65536*17*2
    float* out_conf = out + 2228224;       // 65536*17
    float* out_dist = out + 3342336;       // 65536*5*17
    float* out_class = out + 8912896;      // 65536
    float* out_proto = out + 8978432;      // 5*17*512

    char* ws = (char*)d_ws;
    float* ws_h = (float*)ws;                              // 25*512 f32
    float* ws_proto = (float*)(ws + 51200);                // 5*512 f32
    float* ws_pn = (float*)(ws + 61440);                   // 5 f32
    unsigned short* ws_wb = (unsigned short*)(ws + 65536); // 512*512 bf16 (transposed [Wo1|Wc1])
    float* ws_h1 = (float*)(ws + 589824);                  // 25*512 f32 (hidden layer)

    hipLaunchKernelGGL(k_sup, dim3(3200), dim3(256), 0, stream, sf, W1, b1, ws_h1, 1);
    hipLaunchKernelGGL(k_sup, dim3(3200), dim3(256), 0, stream, ws_h1, W2, b2, ws_h, 0);
    hipLaunchKernelGGL(k_proto, dim3(5), dim3(256), 0, stream, ws_h, ws_proto, ws_pn, out_proto);
    hipLaunchKernelGGL(k_convw, dim3(512), dim3(256), 0, stream, Wo1, Wc1, ws_wb);
    hipLaunchKernelGGL(k_dist, dim3(1024), dim3(256), 0, stream, qf, ws_proto, ws_pn, temp, out_dist, out_class);
    hipLaunchKernelGGL(k_gemm, dim3(2048), dim3(256), 0, stream, qf, ws_wb, bo1, Wo2, bo2, bc1, Wc2, bc2, ic, out_kp, out_conf);
}

// Round 3
// 395.473 us; speedup vs baseline: 1.1969x; 1.0076x over previous
//
#include <hip/hip_runtime.h>
#include <hip/hip_bf16.h>

#define NQ 65536
#define DIM 512
#define HID 256
#define NWAY 5
#define NKPTS 17
#define NS 25

typedef short bf16x8 __attribute__((ext_vector_type(8)));
typedef float f32x4 __attribute__((ext_vector_type(4)));
typedef _Float16 half8 __attribute__((ext_vector_type(8)));

static __device__ __forceinline__ unsigned short f2bf(float f) {
    unsigned int x = __float_as_uint(f);
    unsigned int r = (x + 0x7fffu + ((x >> 16) & 1u)) >> 16;
    return (unsigned short)r;
}

// ---------------- support MLP layer: out[s][c] = (relu?) (in[s]·W[:,c] + b[c]) ----------------
// wave-per-output: 25*512 = 12800 waves = 3200 blocks x 4 waves.
__global__ __launch_bounds__(256) void k_sup(const float* __restrict__ in,
                                             const float* __restrict__ W, const float* __restrict__ b,
                                             float* __restrict__ out, int relu) {
    int w = blockIdx.x * 4 + (threadIdx.x >> 6);   // 0..12799
    int lane = threadIdx.x & 63;
    int s = w >> 9;          // 0..24
    int c = w & 511;         // 0..511
    const float* ip = in + s * DIM + lane * 8;
    float4 a0 = *(const float4*)ip;
    float4 a1 = *(const float4*)(ip + 4);
    float av[8] = {a0.x, a0.y, a0.z, a0.w, a1.x, a1.y, a1.z, a1.w};
    float acc = 0.0f;
    #pragma unroll
    for (int j = 0; j < 8; j++)
        acc += av[j] * W[(lane * 8 + j) * DIM + c];
    #pragma unroll
    for (int off = 32; off > 0; off >>= 1)
        acc += __shfl_xor(acc, off, 64);
    if (lane == 0) {
        float v = acc + b[c];
        out[s * DIM + c] = relu ? fmaxf(v, 0.0f) : v;
    }
}

// ---------------- prototypes: mean over shots, norm, broadcast out ----------------
__global__ __launch_bounds__(256) void k_proto(const float* __restrict__ ws_h,
                                               float* __restrict__ ws_proto, float* __restrict__ ws_pn,
                                               float* __restrict__ out_proto) {
    int w = blockIdx.x, t = threadIdx.x;
    __shared__ float s_p[DIM];
    __shared__ float red[256];
    for (int i = t; i < DIM; i += 256) {
        float a = 0.0f;
        for (int s = 0; s < 5; s++) a += ws_h[(w * 5 + s) * DIM + i];
        a *= 0.2f;
        s_p[i] = a;
        ws_proto[w * DIM + i] = a;
    }
    __syncthreads();
    float qq = 0.0f;
    for (int i = t; i < DIM; i += 256) qq += s_p[i] * s_p[i];
    red[t] = qq;
    __syncthreads();
    for (int s2 = 128; s2 > 0; s2 >>= 1) {
        if (t < s2) red[t] += red[t + s2];
        __syncthreads();
    }
    if (t == 0) ws_pn[w] = sqrtf(red[0]);
    for (int i = t; i < NKPTS * DIM; i += 256)
        out_proto[(size_t)w * NKPTS * DIM + i] = s_p[i & (DIM - 1)];
}

// ---------------- convert [Wo1|Wc1] -> bf16, transposed: wb[c*512+k] = W[k][c] ----------------
__global__ __launch_bounds__(256) void k_convw(const float* __restrict__ Wo1, const float* __restrict__ Wc1,
                                               unsigned short* __restrict__ wb) {
    int c = blockIdx.x;
    const float* src = (c < 256) ? Wo1 : Wc1;
    int cc = (c < 256) ? c : (c - 256);
    for (int k = threadIdx.x; k < DIM; k += 256)
        wb[c * DIM + k] = f2bf(src[k * HID + cc]);
}

// ---------------- fused MFMA GEMM + distances + head epilogue ----------------
// grid: (NQ/64) * 2 blocks; nb=0 -> offset head + distances; nb=1 -> confidence head
// K-loop uses register prefetch: iter+1 global loads issued right after the store
// barrier so HBM latency overlaps ds_read+MFMA (the m97 barrier-drain lesson).
__global__ __launch_bounds__(256, 2) void k_fused(const float* __restrict__ qf, const unsigned short* __restrict__ wb,
                                                  const float* __restrict__ ws_proto, const float* __restrict__ ws_pn,
                                                  const float* __restrict__ temp_p,
                                                  const float* __restrict__ bo1, const float* __restrict__ Wo2,
                                                  const float* __restrict__ bo2,
                                                  const float* __restrict__ bc1, const float* __restrict__ Wc2,
                                                  const float* __restrict__ bc2,
                                                  const float* __restrict__ ic,
                                                  float* __restrict__ out_kp, float* __restrict__ out_conf,
                                                  float* __restrict__ out_dist, float* __restrict__ out_class) {
    __shared__ __align__(16) char smem[37120];
    unsigned short* Alds = (unsigned short*)smem;            // 64 rows x stride 40 bf16       [0, 5120)
    unsigned short* Blds = (unsigned short*)(smem + 5120);   // 256 rows x stride 40 bf16      [5120, 25600)
    float* s_proto = (float*)(smem + 25600);                 // 5 x 512 f32                    [25600, 35840)
    float* dlds = (float*)(smem + 35840);                    // 64 x 5 f32                     [35840, 37120)
    _Float16* hlds = (_Float16*)smem;                        // epilogue: 64 x stride 264 f16  [0, 33792)
    float* offlds = (float*)(smem + 33792);                  // 128 f32                        [33792, 34304)

    int bx = blockIdx.x;
    int mb = bx >> 1;
    int nb = bx & 1;
    int t = threadIdx.x;
    int wv = t >> 6;
    int lane = t & 63;
    int r = lane & 15;
    int q8 = (lane >> 4) * 8;

    f32x4 acc[4][4];
    #pragma unroll
    for (int i = 0; i < 4; i++)
        #pragma unroll
        for (int j = 0; j < 4; j++) {
            f32x4 z = {0.0f, 0.0f, 0.0f, 0.0f};
            acc[i][j] = z;
        }

    int am = t >> 2;   // A row this thread stages (0..63), 4 threads per row
    int akc = t & 3;   // k-chunk within 32 (akc*8)
    const float* aptr = qf + ((size_t)(mb * 64 + am)) * DIM + akc * 8;
    const unsigned short* bptr = wb + ((size_t)(nb * 256 + t)) * DIM;

    if (nb == 0)
        for (int i = t; i < NWAY * DIM; i += 256) s_proto[i] = ws_proto[i];

    float ds[NWAY] = {0, 0, 0, 0, 0};
    float qq = 0.0f;

    // prefetch iter 0
    float4 A0 = *(const float4*)(aptr);
    float4 A1 = *(const float4*)(aptr + 4);
    uint4 B0 = *(const uint4*)(bptr);
    uint4 B1 = *(const uint4*)(bptr + 8);
    uint4 B2 = *(const uint4*)(bptr + 16);
    uint4 B3 = *(const uint4*)(bptr + 24);

    for (int it = 0; it < 16; it++) {
        unsigned int p0 = f2bf(A0.x) | ((unsigned int)f2bf(A0.y) << 16);
        unsigned int p1 = f2bf(A0.z) | ((unsigned int)f2bf(A0.w) << 16);
        unsigned int p2 = f2bf(A1.x) | ((unsigned int)f2bf(A1.y) << 16);
        unsigned int p3 = f2bf(A1.z) | ((unsigned int)f2bf(A1.w) << 16);
        float av[8] = {A0.x, A0.y, A0.z, A0.w, A1.x, A1.y, A1.z, A1.w};
        __syncthreads();  // previous iter's frag/proto reads complete
        *(uint4*)(Alds + am * 40 + akc * 8) = make_uint4(p0, p1, p2, p3);
        *(uint4*)(Blds + t * 40) = B0;
        *(uint4*)(Blds + t * 40 + 8) = B1;
        *(uint4*)(Blds + t * 40 + 16) = B2;
        *(uint4*)(Blds + t * 40 + 24) = B3;
        __syncthreads();
        if (it < 15) {  // issue next-iter global loads; latency overlaps below
            int k1 = (it + 1) * 32;
            A0 = *(const float4*)(aptr + k1);
            A1 = *(const float4*)(aptr + k1 + 4);
            B0 = *(const uint4*)(bptr + k1);
            B1 = *(const uint4*)(bptr + k1 + 8);
            B2 = *(const uint4*)(bptr + k1 + 16);
            B3 = *(const uint4*)(bptr + k1 + 24);
        }
        if (nb == 0) {  // f32 distance partials from this thread's A slice
            int kb = it * 32 + akc * 8;
            #pragma unroll
            for (int w = 0; w < NWAY; w++) {
                f32x4 pv0 = *(const f32x4*)(s_proto + w * DIM + kb);
                f32x4 pv1 = *(const f32x4*)(s_proto + w * DIM + kb + 4);
                ds[w] += av[0] * pv0[0] + av[1] * pv0[1] + av[2] * pv0[2] + av[3] * pv0[3]
                       + av[4] * pv1[0] + av[5] * pv1[1] + av[6] * pv1[2] + av[7] * pv1[3];
            }
            #pragma unroll
            for (int j = 0; j < 8; j++) qq += av[j] * av[j];
        }
        bf16x8 af[4], bf[4];
        #pragma unroll
        for (int mt = 0; mt < 4; mt++)
            af[mt] = *(const bf16x8*)(Alds + (mt * 16 + r) * 40 + q8);
        #pragma unroll
        for (int nt = 0; nt < 4; nt++)
            bf[nt] = *(const bf16x8*)(Blds + (wv * 64 + nt * 16 + r) * 40 + q8);
        #pragma unroll
        for (int mt = 0; mt < 4; mt++)
            #pragma unroll
            for (int nt = 0; nt < 4; nt++)
                acc[mt][nt] = __builtin_amdgcn_mfma_f32_16x16x32_bf16(af[mt], bf[nt], acc[mt][nt], 0, 0, 0);
    }

    // ---- finalize distances (nb==0): reduce over the 4 threads sharing a row ----
    if (nb == 0) {
        #pragma unroll
        for (int off = 1; off <= 2; off <<= 1) {
            #pragma unroll
            for (int w = 0; w < NWAY; w++) ds[w] += __shfl_xor(ds[w], off, 64);
            qq += __shfl_xor(qq, off, 64);
        }
        if (akc == 0) {
            float qn = sqrtf(qq);
            float invt = 1.0f / temp_p[0];
            float mv = 1e30f;
            int ami = 0;
            #pragma unroll
            for (int w = 0; w < NWAY; w++) {
                float den = fmaxf(qn * ws_pn[w], 1e-8f);
                float d = (1.0f - ds[w] / den) * invt;
                dlds[am * 5 + w] = d;
                if (d < mv) { mv = d; ami = w; }
            }
            out_class[mb * 64 + am] = (float)ami;
        }
    }
    __syncthreads();  // dlds ready; Alds/Blds/proto regions dead -> hlds reuse safe
    if (nb == 0) {
        for (int i = t; i < 64 * NWAY * NKPTS; i += 256) {
            int q = i / (NWAY * NKPTS);
            int rem = i - q * (NWAY * NKPTS);
            out_dist[(size_t)(mb * 64 + q) * (NWAY * NKPTS) + rem] = dlds[q * 5 + rem / NKPTS];
        }
    }

    // ---- bias + relu + store h tile to LDS as f16 (C layout: row=(lane>>4)*4+rg, col=lane&15) ----
    const float* bias = nb ? bc1 : bo1;
    #pragma unroll
    for (int nt = 0; nt < 4; nt++) {
        int cl = wv * 64 + nt * 16 + r;  // 0..255
        float bv = bias[cl];
        #pragma unroll
        for (int mt = 0; mt < 4; mt++)
            #pragma unroll
            for (int rg = 0; rg < 4; rg++) {
                int ml = mt * 16 + (lane >> 4) * 4 + rg;
                float v = acc[mt][nt][rg] + bv;
                hlds[ml * 264 + cl] = (_Float16)fmaxf(v, 0.0f);
            }
    }
    __syncthreads();

    if (nb == 0) {
        if (t < 64) {
            float ox = bo2[0], oy = bo2[1];
            for (int c0 = 0; c0 < 256; c0 += 8) {
                half8 hv = *(const half8*)(hlds + t * 264 + c0);
                #pragma unroll
                for (int j = 0; j < 8; j++) {
                    float hf = (float)hv[j];
                    ox += hf * Wo2[(c0 + j) * 2];
                    oy += hf * Wo2[(c0 + j) * 2 + 1];
                }
            }
            offlds[t * 2] = ox;
            offlds[t * 2 + 1] = oy;
        }
        __syncthreads();
        for (int i = t; i < 64 * 34; i += 256) {
            int q = i / 34;
            int rem = i - q * 34;
            int j = rem & 1;
            size_t Q = (size_t)mb * 64 + q;
            float o = offlds[q * 2 + j];
            float sg = 1.0f / (1.0f + __expf(-o));
            out_kp[Q * 34 + rem] = sg * ic[Q * 2 + j];
        }
    } else {
        if (t < 64) {
            float cl2 = bc2[0];
            for (int c0 = 0; c0 < 256; c0 += 8) {
                half8 hv = *(const half8*)(hlds + t * 264 + c0);
                #pragma unroll
                for (int j = 0; j < 8; j++) cl2 += (float)hv[j] * Wc2[c0 + j];
            }
            offlds[t] = 1.0f / (1.0f + __expf(-cl2));
        }
        __syncthreads();
        for (int i = t; i < 64 * 17; i += 256) {
            int q = i / 17;
            out_conf[(size_t)mb * 64 * 17 + i] = offlds[q];
        }
    }
}

extern "C" void kernel_launch(void* const* d_in, const int* in_sizes, int n_in,
                              void* d_out, int out_size, void* d_ws, size_t ws_size,
                              hipStream_t stream) {
    const float* sf = (const float*)d_in[0];
    const float* qf = (const float*)d_in[2];
    const float* ic = (const float*)d_in[3];
    const float* W1 = (const float*)d_in[4];
    const float* b1 = (const float*)d_in[5];
    const float* W2 = (const float*)d_in[6];
    const float* b2 = (const float*)d_in[7];
    const float* Wo1 = (const float*)d_in[8];
    const float* bo1 = (const float*)d_in[9];
    const float* Wo2 = (const float*)d_in[10];
    const float* bo2 = (const float*)d_in[11];
    const float* Wc1 = (const float*)d_in[12];
    const float* bc1 = (const float*)d_in[13];
    const float* Wc2 = (const float*)d_in[14];
    const float* bc2 = (const float*)d_in[15];
    const float* temp = (const float*)d_in[16];

    float* out = (float*)d_out;
    float* out_kp = out;                   // 65536*17*2
    float* out_conf = out + 2228224;       // 65536*17
    float* out_dist = out + 3342336;       // 65536*5*17
    float* out_class = out + 8912896;      // 65536
    float* out_proto = out + 8978432;      // 5*17*512

    char* ws = (char*)d_ws;
    float* ws_h = (float*)ws;                              // 25*512 f32
    float* ws_proto = (float*)(ws + 51200);                // 5*512 f32
    float* ws_pn = (float*)(ws + 61440);                   // 5 f32
    unsigned short* ws_wb = (unsigned short*)(ws + 65536); // 512*512 bf16 (transposed [Wo1|Wc1])
    float* ws_h1 = (float*)(ws + 589824);                  // 25*512 f32 (hidden layer)

    hipLaunchKernelGGL(k_sup, dim3(3200), dim3(256), 0, stream, sf, W1, b1, ws_h1, 1);
    hipLaunchKernelGGL(k_sup, dim3(3200), dim3(256), 0, stream, ws_h1, W2, b2, ws_h, 0);
    hipLaunchKernelGGL(k_proto, dim3(5), dim3(256), 0, stream, ws_h, ws_proto, ws_pn, out_proto);
    hipLaunchKernelGGL(k_convw, dim3(512), dim3(256), 0, stream, Wo1, Wc1, ws_wb);
    hipLaunchKernelGGL(k_fused, dim3(2048), dim3(256), 0, stream, qf, ws_wb, ws_proto, ws_pn, temp,
                       bo1, Wo2, bo2, bc1, Wc2, bc2, ic, out_kp, out_conf, out_dist, out_class);
}

// Round 4
// 366.077 us; speedup vs baseline: 1.2930x; 1.0803x over previous
//
#include <hip/hip_runtime.h>
#include <hip/hip_bf16.h>

#define NQ 65536
#define DIM 512
#define HID 256
#define NWAY 5
#define NKPTS 17

typedef short bf16x8 __attribute__((ext_vector_type(8)));
typedef float f32x4 __attribute__((ext_vector_type(4)));
typedef _Float16 half8 __attribute__((ext_vector_type(8)));

static __device__ __forceinline__ unsigned short f2bf(float f) {
    unsigned int x = __float_as_uint(f);
    unsigned int r = (x + 0x7fffu + ((x >> 16) & 1u)) >> 16;
    return (unsigned short)r;
}

// ---------------- layer 1 of support MLP: ws_h1 = relu(sf@W1+b1), 25x512 ----------------
// wave-per-output: 25*512 = 12800 waves = 3200 blocks x 4 waves.
__global__ __launch_bounds__(256) void k_sup1(const float* __restrict__ sf,
                                              const float* __restrict__ W1, const float* __restrict__ b1,
                                              float* __restrict__ ws_h1) {
    int w = blockIdx.x * 4 + (threadIdx.x >> 6);   // 0..12799
    int lane = threadIdx.x & 63;
    int s = w >> 9;          // 0..24
    int c = w & 511;         // 0..511
    const float* ip = sf + s * DIM + lane * 8;
    float4 a0 = *(const float4*)ip;
    float4 a1 = *(const float4*)(ip + 4);
    float av[8] = {a0.x, a0.y, a0.z, a0.w, a1.x, a1.y, a1.z, a1.w};
    float acc = 0.0f;
    #pragma unroll
    for (int j = 0; j < 8; j++)
        acc += av[j] * W1[(lane * 8 + j) * DIM + c];
    #pragma unroll
    for (int off = 32; off > 0; off >>= 1)
        acc += __shfl_xor(acc, off, 64);
    if (lane == 0)
        ws_h1[s * DIM + c] = fmaxf(acc + b1[c], 0.0f);
}

// ---------------- k_mid: prototypes (mean commutes with linear layer 2) + weight transpose ----
// bx < 640 : proto_way[w][c] = (mean_s relu1[w*5+s]) @ W2[:,c] + b2[c]   (wave per (w,c))
// bx >= 640: 64x64 tile transpose+bf16 of [Wo1|Wc1] -> wb[c*512+k]
__global__ __launch_bounds__(256) void k_mid(const float* __restrict__ ws_h1,
                                             const float* __restrict__ W2, const float* __restrict__ b2,
                                             const float* __restrict__ Wo1, const float* __restrict__ Wc1,
                                             float* __restrict__ ws_proto, unsigned short* __restrict__ wb) {
    int bx = blockIdx.x;
    int t = threadIdx.x;
    if (bx < 640) {
        int g = bx * 4 + (t >> 6);   // 0..2559
        int lane = t & 63;
        int w = g >> 9;              // 0..4
        int c = g & 511;             // 0..511
        const float* base = ws_h1 + (w * 5) * DIM + lane * 8;
        float av[8] = {0, 0, 0, 0, 0, 0, 0, 0};
        #pragma unroll
        for (int s = 0; s < 5; s++) {
            float4 x0 = *(const float4*)(base + s * DIM);
            float4 x1 = *(const float4*)(base + s * DIM + 4);
            av[0] += x0.x; av[1] += x0.y; av[2] += x0.z; av[3] += x0.w;
            av[4] += x1.x; av[5] += x1.y; av[6] += x1.z; av[7] += x1.w;
        }
        float acc = 0.0f;
        #pragma unroll
        for (int j = 0; j < 8; j++)
            acc += (av[j] * 0.2f) * W2[(lane * 8 + j) * DIM + c];
        #pragma unroll
        for (int off = 32; off > 0; off >>= 1)
            acc += __shfl_xor(acc, off, 64);
        if (lane == 0)
            ws_proto[w * DIM + c] = acc + b2[c];
    } else {
        __shared__ unsigned short T[64][72];
        int tb = bx - 640;                   // 0..63
        const float* src = (tb < 32) ? Wo1 : Wc1;
        int cofs = (tb < 32) ? 0 : 256;
        int tt = tb & 31;
        int kt = tt >> 2;                    // k-tile 0..7
        int ct = tt & 3;                     // c-tile 0..3
        int i = t >> 2;                      // k row within tile 0..63
        int qd = t & 3;
        const float* rp = src + (size_t)(kt * 64 + i) * HID + ct * 64 + qd * 16;
        #pragma unroll
        for (int v = 0; v < 4; v++) {
            float4 x = *(const float4*)(rp + v * 4);
            T[qd * 16 + v * 4 + 0][i] = f2bf(x.x);
            T[qd * 16 + v * 4 + 1][i] = f2bf(x.y);
            T[qd * 16 + v * 4 + 2][i] = f2bf(x.z);
            T[qd * 16 + v * 4 + 3][i] = f2bf(x.w);
        }
        __syncthreads();
        int j = t >> 2;                      // c within tile
        int part = t & 3;
        uint4 o0 = *(const uint4*)&T[j][part * 16];
        uint4 o1 = *(const uint4*)&T[j][part * 16 + 8];
        unsigned short* dst = wb + (size_t)(cofs + ct * 64 + j) * DIM + kt * 64 + part * 16;
        *(uint4*)dst = o0;
        *(uint4*)(dst + 8) = o1;
    }
}

// ---------------- fused MFMA GEMM + balanced distances + head epilogue ----------------
// grid: (NQ/64)*2; nb=0 -> offset head + dists for tile queries [0,32); nb=1 -> conf head + [32,64)
__global__ __launch_bounds__(256) void k_fused(const float* __restrict__ qf, const unsigned short* __restrict__ wb,
                                               const float* __restrict__ ws_proto,
                                               const float* __restrict__ temp_p,
                                               const float* __restrict__ bo1, const float* __restrict__ Wo2,
                                               const float* __restrict__ bo2,
                                               const float* __restrict__ bc1, const float* __restrict__ Wc2,
                                               const float* __restrict__ bc2,
                                               const float* __restrict__ ic,
                                               float* __restrict__ out_kp, float* __restrict__ out_conf,
                                               float* __restrict__ out_dist, float* __restrict__ out_class,
                                               float* __restrict__ out_proto) {
    __shared__ __align__(16) char smem[37376];
    unsigned short* Alds = (unsigned short*)smem;            // 64 x stride 40 bf16            [0, 5120)
    unsigned short* Blds = (unsigned short*)(smem + 5120);   // 256 x stride 40 bf16           [5120, 25600)
    float* s_proto = (float*)(smem + 25600);                 // 5 x 512 f32                    [25600, 35840)
    float* dlds = (float*)(smem + 35840);                    // 64 x 5 f32                     [35840, 37120)
    float* pn_lds = (float*)(smem + 37120);                  // 5 f32                          [37120, 37140)
    _Float16* hlds = (_Float16*)smem;                        // epilogue: 64 x stride 264 f16  [0, 33792)
    float* offlds = (float*)(smem + 33792);                  // 128 f32

    int bx = blockIdx.x;
    int mb = bx >> 1;
    int nb = bx & 1;
    int t = threadIdx.x;
    int wv = t >> 6;
    int lane = t & 63;
    int r = lane & 15;
    int q8 = (lane >> 4) * 8;

    // out_proto broadcast, spread over blocks 0..84 (one float4/thread, reads global ws_proto)
    if (bx < 85 && t < 128) {
        f32x4 v = *(const f32x4*)(ws_proto + (bx / NKPTS) * DIM + t * 4);
        *(f32x4*)(out_proto + (size_t)bx * DIM + t * 4) = v;
    }

    f32x4 acc[4][4];
    #pragma unroll
    for (int i = 0; i < 4; i++)
        #pragma unroll
        for (int j = 0; j < 4; j++) {
            f32x4 z = {0.0f, 0.0f, 0.0f, 0.0f};
            acc[i][j] = z;
        }

    int am = t >> 2;   // A row this thread stages (0..63), 4 threads per row
    int akc = t & 3;   // k-chunk within 32 (akc*8)
    int mine = ((t >> 7) == nb);  // this thread's row belongs to this block's dist half (wave-uniform)
    const float* aptr = qf + ((size_t)(mb * 64 + am)) * DIM + akc * 8;
    const unsigned short* bptr = wb + ((size_t)(nb * 256 + t)) * DIM;

    for (int i = t; i < NWAY * DIM; i += 256) s_proto[i] = ws_proto[i];

    float ds[NWAY] = {0, 0, 0, 0, 0};
    float qq = 0.0f;

    // prefetch iter 0
    float4 A0 = *(const float4*)(aptr);
    float4 A1 = *(const float4*)(aptr + 4);
    uint4 B0 = *(const uint4*)(bptr);
    uint4 B1 = *(const uint4*)(bptr + 8);
    uint4 B2 = *(const uint4*)(bptr + 16);
    uint4 B3 = *(const uint4*)(bptr + 24);

    for (int it = 0; it < 16; it++) {
        unsigned int p0 = f2bf(A0.x) | ((unsigned int)f2bf(A0.y) << 16);
        unsigned int p1 = f2bf(A0.z) | ((unsigned int)f2bf(A0.w) << 16);
        unsigned int p2 = f2bf(A1.x) | ((unsigned int)f2bf(A1.y) << 16);
        unsigned int p3 = f2bf(A1.z) | ((unsigned int)f2bf(A1.w) << 16);
        float av[8] = {A0.x, A0.y, A0.z, A0.w, A1.x, A1.y, A1.z, A1.w};
        __syncthreads();  // previous iter's frag/proto reads complete
        *(uint4*)(Alds + am * 40 + akc * 8) = make_uint4(p0, p1, p2, p3);
        *(uint4*)(Blds + t * 40) = B0;
        *(uint4*)(Blds + t * 40 + 8) = B1;
        *(uint4*)(Blds + t * 40 + 16) = B2;
        *(uint4*)(Blds + t * 40 + 24) = B3;
        __syncthreads();
        if (it < 15) {  // next-iter global loads stay in flight over the MFMA body
            int k1 = (it + 1) * 32;
            A0 = *(const float4*)(aptr + k1);
            A1 = *(const float4*)(aptr + k1 + 4);
            B0 = *(const uint4*)(bptr + k1);
            B1 = *(const uint4*)(bptr + k1 + 8);
            B2 = *(const uint4*)(bptr + k1 + 16);
            B3 = *(const uint4*)(bptr + k1 + 24);
        }
        if (mine) {  // f32 distance partials for this block's query half
            int kb = it * 32 + akc * 8;
            #pragma unroll
            for (int w = 0; w < NWAY; w++) {
                f32x4 pv0 = *(const f32x4*)(s_proto + w * DIM + kb);
                f32x4 pv1 = *(const f32x4*)(s_proto + w * DIM + kb + 4);
                ds[w] += av[0] * pv0[0] + av[1] * pv0[1] + av[2] * pv0[2] + av[3] * pv0[3]
                       + av[4] * pv1[0] + av[5] * pv1[1] + av[6] * pv1[2] + av[7] * pv1[3];
            }
            #pragma unroll
            for (int j = 0; j < 8; j++) qq += av[j] * av[j];
        }
        bf16x8 af[4], bf[4];
        #pragma unroll
        for (int mt = 0; mt < 4; mt++)
            af[mt] = *(const bf16x8*)(Alds + (mt * 16 + r) * 40 + q8);
        #pragma unroll
        for (int nt = 0; nt < 4; nt++)
            bf[nt] = *(const bf16x8*)(Blds + (wv * 64 + nt * 16 + r) * 40 + q8);
        #pragma unroll
        for (int mt = 0; mt < 4; mt++)
            #pragma unroll
            for (int nt = 0; nt < 4; nt++)
                acc[mt][nt] = __builtin_amdgcn_mfma_f32_16x16x32_bf16(af[mt], bf[nt], acc[mt][nt], 0, 0, 0);
    }

    // ---- proto norms (per block, from staged s_proto): wave wv handles ways wv, wv+4 ----
    for (int w = wv; w < NWAY; w += 4) {
        f32x4 a = *(const f32x4*)(s_proto + w * DIM + lane * 8);
        f32x4 b = *(const f32x4*)(s_proto + w * DIM + lane * 8 + 4);
        float ss = a[0]*a[0] + a[1]*a[1] + a[2]*a[2] + a[3]*a[3]
                 + b[0]*b[0] + b[1]*b[1] + b[2]*b[2] + b[3]*b[3];
        #pragma unroll
        for (int off = 32; off > 0; off >>= 1) ss += __shfl_xor(ss, off, 64);
        if (lane == 0) pn_lds[w] = sqrtf(ss);
    }
    // ---- reduce dist partials over the 4 threads sharing a row ----
    if (mine) {
        #pragma unroll
        for (int off = 1; off <= 2; off <<= 1) {
            #pragma unroll
            for (int w = 0; w < NWAY; w++) ds[w] += __shfl_xor(ds[w], off, 64);
            qq += __shfl_xor(qq, off, 64);
        }
    }
    __syncthreads();  // pn_lds ready
    if (mine && akc == 0) {
        float qn = sqrtf(qq);
        float invt = 1.0f / temp_p[0];
        float mv = 1e30f;
        int ami = 0;
        #pragma unroll
        for (int w = 0; w < NWAY; w++) {
            float den = fmaxf(qn * pn_lds[w], 1e-8f);
            float d = (1.0f - ds[w] / den) * invt;
            dlds[am * 5 + w] = d;
            if (d < mv) { mv = d; ami = w; }
        }
        out_class[mb * 64 + am] = (float)ami;
    }
    __syncthreads();  // dlds ready; s_proto dead -> hlds reuse safe

    // dist out-write for this block's half (reads dlds; disjoint LDS from hlds writes below)
    {
        int qlo = nb * 32;
        for (int i = t; i < 32 * NWAY * NKPTS; i += 256) {
            int q = qlo + i / (NWAY * NKPTS);
            int rem = i - (i / (NWAY * NKPTS)) * (NWAY * NKPTS);
            out_dist[(size_t)(mb * 64 + q) * (NWAY * NKPTS) + rem] = dlds[q * 5 + rem / NKPTS];
        }
    }

    // ---- bias + relu + store h tile to LDS as f16 (C layout: row=(lane>>4)*4+rg, col=lane&15) ----
    const float* bias = nb ? bc1 : bo1;
    #pragma unroll
    for (int nt = 0; nt < 4; nt++) {
        int cl = wv * 64 + nt * 16 + r;  // 0..255
        float bv = bias[cl];
        #pragma unroll
        for (int mt = 0; mt < 4; mt++)
            #pragma unroll
            for (int rg = 0; rg < 4; rg++) {
                int ml = mt * 16 + (lane >> 4) * 4 + rg;
                float v = acc[mt][nt][rg] + bv;
                hlds[ml * 264 + cl] = (_Float16)fmaxf(v, 0.0f);
            }
    }
    __syncthreads();

    if (nb == 0) {
        if (t < 64) {
            float ox = bo2[0], oy = bo2[1];
            for (int c0 = 0; c0 < 256; c0 += 8) {
                half8 hv = *(const half8*)(hlds + t * 264 + c0);
                #pragma unroll
                for (int j = 0; j < 8; j++) {
                    float hf = (float)hv[j];
                    ox += hf * Wo2[(c0 + j) * 2];
                    oy += hf * Wo2[(c0 + j) * 2 + 1];
                }
            }
            offlds[t * 2] = ox;
            offlds[t * 2 + 1] = oy;
        }
        __syncthreads();
        for (int i = t; i < 64 * 34; i += 256) {
            int q = i / 34;
            int rem = i - q * 34;
            int j = rem & 1;
            size_t Q = (size_t)mb * 64 + q;
            float o = offlds[q * 2 + j];
            float sg = 1.0f / (1.0f + __expf(-o));
            out_kp[Q * 34 + rem] = sg * ic[Q * 2 + j];
        }
    } else {
        if (t < 64) {
            float cl2 = bc2[0];
            for (int c0 = 0; c0 < 256; c0 += 8) {
                half8 hv = *(const half8*)(hlds + t * 264 + c0);
                #pragma unroll
                for (int j = 0; j < 8; j++) cl2 += (float)hv[j] * Wc2[c0 + j];
            }
            offlds[t] = 1.0f / (1.0f + __expf(-cl2));
        }
        __syncthreads();
        for (int i = t; i < 64 * 17; i += 256) {
            int q = i / 17;
            out_conf[(size_t)mb * 64 * 17 + i] = offlds[q];
        }
    }
}

extern "C" void kernel_launch(void* const* d_in, const int* in_sizes, int n_in,
                              void* d_out, int out_size, void* d_ws, size_t ws_size,
                              hipStream_t stream) {
    const float* sf = (const float*)d_in[0];
    const float* qf = (const float*)d_in[2];
    const float* ic = (const float*)d_in[3];
    const float* W1 = (const float*)d_in[4];
    const float* b1 = (const float*)d_in[5];
    const float* W2 = (const float*)d_in[6];
    const float* b2 = (const float*)d_in[7];
    const float* Wo1 = (const float*)d_in[8];
    const float* bo1 = (const float*)d_in[9];
    const float* Wo2 = (const float*)d_in[10];
    const float* bo2 = (const float*)d_in[11];
    const float* Wc1 = (const float*)d_in[12];
    const float* bc1 = (const float*)d_in[13];
    const float* Wc2 = (const float*)d_in[14];
    const float* bc2 = (const float*)d_in[15];
    const float* temp = (const float*)d_in[16];

    float* out = (float*)d_out;
    float* out_kp = out;                   // 65536*17*2
    float* out_conf = out + 2228224;       // 65536*17
    float* out_dist = out + 3342336;       // 65536*5*17
    float* out_class = out + 8912896;      // 65536
    float* out_proto = out + 8978432;      // 5*17*512

    char* ws = (char*)d_ws;
    float* ws_h1 = (float*)ws;                             // 25*512 f32
    float* ws_proto = (float*)(ws + 51200);                // 5*512 f32
    unsigned short* ws_wb = (unsigned short*)(ws + 65536); // 512*512 bf16 (transposed [Wo1|Wc1])

    hipLaunchKernelGGL(k_sup1, dim3(3200), dim3(256), 0, stream, sf, W1, b1, ws_h1);
    hipLaunchKernelGGL(k_mid, dim3(704), dim3(256), 0, stream, ws_h1, W2, b2, Wo1, Wc1, ws_proto, ws_wb);
    hipLaunchKernelGGL(k_fused, dim3(2048), dim3(256), 0, stream, qf, ws_wb, ws_proto, temp,
                       bo1, Wo2, bo2, bc1, Wc2, bc2, ic, out_kp, out_conf, out_dist, out_class, out_proto);
}